// Round 6
// baseline (374.492 us; speedup 1.0000x reference)
//
#include <hip/hip_runtime.h>
#include <hip/hip_bf16.h>

#define NH 16
#define HD 64
#define SEQ 2048
#define HID 1024
#define MAXP 2048
#define ST_R 68   // u16 stride of transposed R tiles (136B: b64-aligned writes)

typedef float f32x4 __attribute__((ext_vector_type(4)));
typedef short bf16x8 __attribute__((ext_vector_type(8)));
typedef unsigned short u16;
typedef unsigned short u16x8 __attribute__((ext_vector_type(8)));

__device__ __forceinline__ u16 f2bf_hw(float x) {
  union { __hip_bfloat16 h; u16 u; } v;
  v.h = __float2bfloat16(x);
  return v.u;
}
__device__ __forceinline__ unsigned pk2(float a, float b) {
  return (unsigned)f2bf_hw(a) | ((unsigned)f2bf_hw(b) << 16);
}
__device__ __forceinline__ float bf2f(u16 h) {
  union { unsigned u; float f; } v; v.u = ((unsigned)h) << 16;
  return v.f;
}

// XOR-swizzle for bf16 tiles with 64-elem (128B) row stride.
#define SWZ(r, c) ((r) * 64 + ((((c) >> 3) ^ ((r) & 7)) << 3) + ((c) & 7))

// async global->LDS 16B: LDS dest = wave-uniform base + lane*16; global src per-lane.
__device__ __forceinline__ void async_copy16(void* lds, const void* g) {
  __builtin_amdgcn_global_load_lds(
      (const __attribute__((address_space(1))) unsigned int*)g,
      (__attribute__((address_space(3))) unsigned int*)lds, 16, 0, 0);
}

// ---------------- fp32 -> bf16 bulk convert ----------------
__global__ __launch_bounds__(256) void cvt_f32_bf16(
    const float* __restrict__ src, u16* __restrict__ dst, int n4) {
  int i = blockIdx.x * 256 + threadIdx.x;
  const int stride = gridDim.x * 256;
  for (; i < n4; i += stride) {
    const float4 v = reinterpret_cast<const float4*>(src)[i];
    uint2 d;
    d.x = pk2(v.x, v.y);
    d.y = pk2(v.z, v.w);
    reinterpret_cast<uint2*>(dst)[i] = d;
  }
}

// ---------------- Fused Q/K/V projection: O = bf16((X @ W^T + b) * scale) ----
// 128x128 tile, BK=64, 4 waves, global_load_lds staging, pre-swizzled source.
// Q (wsel==0) is pre-scaled by 0.125 (exact in bf16) to fold the 1/sqrt(64).
__global__ __launch_bounds__(256) void proj_mfma(
    const u16* __restrict__ Xb, const u16* __restrict__ W0,
    const u16* __restrict__ W1, const u16* __restrict__ W2,
    const float* __restrict__ b0, const float* __restrict__ b1,
    const float* __restrict__ b2,
    u16* __restrict__ O0, u16* __restrict__ O1, u16* __restrict__ O2) {
  __shared__ u16 sA[128 * 64];
  __shared__ u16 sB[128 * 64];
  const int t = threadIdx.x, lane = t & 63, w = t >> 6;
  const int g = lane >> 4, li = lane & 15;
  const int wsel = blockIdx.x >> 3;
  const int n0 = (blockIdx.x & 7) * 128, m0 = blockIdx.y * 128;
  const u16* Wb = wsel == 0 ? W0 : (wsel == 1 ? W1 : W2);
  const float* bias = wsel == 0 ? b0 : (wsel == 1 ? b1 : b2);
  u16* Ob = wsel == 0 ? O0 : (wsel == 1 ? O1 : O2);
  const float oscale = wsel == 0 ? 0.125f : 1.0f;
  const int wr = w >> 1, wc = w & 1;

  f32x4 acc[4][4];
#pragma unroll
  for (int i = 0; i < 4; ++i)
#pragma unroll
    for (int j = 0; j < 4; ++j) acc[i][j] = (f32x4)0.0f;

  for (int k0 = 0; k0 < HID; k0 += 64) {
    __syncthreads();
#pragma unroll
    for (int i = 0; i < 4; ++i) {
      const int idx = (w * 4 + i) * 64 + lane;
      const int row = idx >> 3, sch = (idx & 7) ^ (row & 7);
      async_copy16(&sA[(w * 4 + i) * 512], Xb + (size_t)(m0 + row) * HID + k0 + sch * 8);
      async_copy16(&sB[(w * 4 + i) * 512], Wb + (size_t)(n0 + row) * HID + k0 + sch * 8);
    }
    __syncthreads();
    bf16x8 af[4][2], bfr[4][2];
#pragma unroll
    for (int i = 0; i < 4; ++i)
#pragma unroll
      for (int c = 0; c < 2; ++c)
        af[i][c] = *reinterpret_cast<const bf16x8*>(&sA[SWZ(wr * 64 + 16 * i + li, 32 * c + 8 * g)]);
#pragma unroll
    for (int j = 0; j < 4; ++j)
#pragma unroll
      for (int c = 0; c < 2; ++c)
        bfr[j][c] = *reinterpret_cast<const bf16x8*>(&sB[SWZ(wc * 64 + 16 * j + li, 32 * c + 8 * g)]);
#pragma unroll
    for (int i = 0; i < 4; ++i)
#pragma unroll
      for (int j = 0; j < 4; ++j)
#pragma unroll
        for (int c = 0; c < 2; ++c)
          acc[i][j] = __builtin_amdgcn_mfma_f32_16x16x32_bf16(af[i][c], bfr[j][c], acc[i][j], 0, 0, 0);
  }

#pragma unroll
  for (int j = 0; j < 4; ++j) {
    const float bj = bias[n0 + wc * 64 + 16 * j + li];
#pragma unroll
    for (int i = 0; i < 4; ++i)
#pragma unroll
      for (int r = 0; r < 4; ++r)
        Ob[(size_t)(m0 + wr * 64 + 16 * i + 4 * g + r) * HID + n0 + wc * 64 + 16 * j + li] =
            f2bf_hw((acc[i][j][r] + bj) * oscale);
  }
}

// ---------------- V transpose: Vt[b][h][d][s] <- V[b][s][h*64+d] ----------------
__global__ __launch_bounds__(256) void transpose_v(
    const u16* __restrict__ Vin, u16* __restrict__ Vt) {
  __shared__ u16 tile[64 * 65];
  const int t = threadIdx.x;
  const int s0 = blockIdx.x * 64, h = blockIdx.y, b = blockIdx.z;
  const int r = t >> 2, c0 = (t & 3) * 16;
  const u16* gp = Vin + (size_t)(b * SEQ + s0 + r) * HID + h * HD + c0;
  const u16x8 a0 = *reinterpret_cast<const u16x8*>(gp);
  const u16x8 a1 = *reinterpret_cast<const u16x8*>(gp + 8);
#pragma unroll
  for (int i = 0; i < 8; ++i) { tile[r * 65 + c0 + i] = a0[i]; tile[r * 65 + c0 + 8 + i] = a1[i]; }
  __syncthreads();
  const int d = t >> 2, sc = (t & 3) * 16;
  u16x8 o0, o1;
#pragma unroll
  for (int i = 0; i < 8; ++i) {
    o0[i] = tile[(sc + i) * 65 + d];
    o1[i] = tile[(sc + 8 + i) * 65 + d];
  }
  u16* op = Vt + ((size_t)(b * NH + h) * HD + d) * SEQ + s0 + sc;
  *reinterpret_cast<u16x8*>(op) = o0;
  *reinterpret_cast<u16x8*>(op + 8) = o1;
}

// ---------------- Fused MFMA attention v3 ----------------
// Per block: (b,h,64 q-rows), 4 waves, 50 KB LDS -> 3 blocks/CU.
// Q pre-scaled by 1/8. No-max softmax: p = exp(aqk + relq + relk/8) directly
// (scores bounded ~|s|<3), l-reduction deferred to epilogue, no rescaling.
// Per k-tile: E fragments from GLOBAL (L1/L2-resident window); Rq,Rk GEMMs into
// transposed LDS tiles with k0-invariant write/gather addresses (DS-immediate
// offsets); P tile aliases the dead K tile.
__global__ __launch_bounds__(256, 3) void attn_mfma3(
    const u16* __restrict__ Q, const u16* __restrict__ K,
    const u16* __restrict__ Vt, const u16* __restrict__ E,
    float* __restrict__ out) {
  __shared__ u16 sKP[64 * 64];     // K tile, then (after R-barrier) P tile
  __shared__ u16 sV[64 * 64];
  __shared__ u16 sRq[128 * ST_R];  // [j][qi] transposed
  __shared__ u16 sRk[128 * ST_R];  // [j][ki]

  const int t = threadIdx.x;
  const int lane = t & 63, w = t >> 6;
  const int g = lane >> 4, li = lane & 15;
  const int q0 = blockIdx.x * 64;
  const int h = blockIdx.y, b = blockIdx.z;
  const size_t qkbase = (size_t)b * SEQ * HID + (size_t)h * HD;
  const size_t vtbase = (size_t)(b * NH + h) * HD * SEQ;

  bf16x8 qA[2];
#pragma unroll
  for (int c = 0; c < 2; ++c)
    qA[c] = *reinterpret_cast<const bf16x8*>(
        Q + qkbase + (size_t)(q0 + 16 * w + li) * HID + 32 * c + 8 * g);

  f32x4 accO[4];
  float lsum[4];
#pragma unroll
  for (int n = 0; n < 4; ++n) accO[n] = (f32x4)0.0f;
#pragma unroll
  for (int r = 0; r < 4; ++r) lsum[r] = 0.0f;

  // k0-invariant gather/write bases. j = 63 + qi - ki; biased so all unrolled
  // offsets are non-negative compile-time constants (DS offset immediates).
  const int jb48 = 15 + 16 * w + 4 * g - li;             // (63+qi0-li)-48 >= 0
  const u16* gqp = &sRq[jb48 * ST_R + 16 * w + 4 * g];   // + (48+r-16n)*ST_R + r
  const u16* gkp = &sRk[jb48 * ST_R + li];               // + (48+r-16n)*ST_R + 16n
  u16* rkw = &sRk[li * ST_R + 16 * w + 4 * g];           // + m*16*ST_R
  u16* rqw = &sRq[li * ST_R + 16 * w + 4 * g];

  for (int k0 = 0; k0 < SEQ; k0 += 64) {
    const int eb = 1984 + q0 - k0;   // in [0, 3968]
    __syncthreads();                 // prior-iter PV reads done
    // ---- E fragments direct from global (window shared across 32 blocks) ----
    bf16x8 eB[8][2];
#pragma unroll
    for (int m = 0; m < 8; ++m) {
      const int er = min(eb + 16 * m + li, 2 * MAXP - 2);  // row 4095 (j=127) unused
#pragma unroll
      for (int c = 0; c < 2; ++c)
        eB[m][c] = *reinterpret_cast<const bf16x8*>(E + (size_t)er * HD + 32 * c + 8 * g);
    }
    // ---- stage K, Vt tiles (pre-swizzled source) ----
#pragma unroll
    for (int i = 0; i < 2; ++i) {
      const int idx = (w * 2 + i) * 64 + lane;
      const int row = idx >> 3, sch = (idx & 7) ^ (row & 7);
      async_copy16(&sKP[(w * 2 + i) * 512], K + qkbase + (size_t)(k0 + row) * HID + sch * 8);
      async_copy16(&sV[(w * 2 + i) * 512], Vt + vtbase + (size_t)row * SEQ + k0 + sch * 8);
    }
    __syncthreads();

    // ---- S = Q'.K^T ----
    bf16x8 kA[2];
#pragma unroll
    for (int c = 0; c < 2; ++c)
      kA[c] = *reinterpret_cast<const bf16x8*>(&sKP[SWZ(16 * w + li, 32 * c + 8 * g)]);
    f32x4 aqk[4];
#pragma unroll
    for (int n = 0; n < 4; ++n) {
      aqk[n] = (f32x4)0.0f;
#pragma unroll
      for (int c = 0; c < 2; ++c) {
        const bf16x8 kB = *reinterpret_cast<const bf16x8*>(&sKP[SWZ(16 * n + li, 32 * c + 8 * g)]);
        aqk[n] = __builtin_amdgcn_mfma_f32_16x16x32_bf16(qA[c], kB, aqk[n], 0, 0, 0);
      }
    }
    // ---- Rq = Q'.E^T, Rk = K.E^T; packed b64 writes, transposed [j][col] ----
#pragma unroll
    for (int m = 0; m < 8; ++m) {
      f32x4 ak = (f32x4)0.0f, aq = (f32x4)0.0f;
#pragma unroll
      for (int c = 0; c < 2; ++c) {
        ak = __builtin_amdgcn_mfma_f32_16x16x32_bf16(kA[c], eB[m][c], ak, 0, 0, 0);
        aq = __builtin_amdgcn_mfma_f32_16x16x32_bf16(qA[c], eB[m][c], aq, 0, 0, 0);
      }
      uint2 dk, dq;
      dk.x = pk2(ak[0], ak[1]); dk.y = pk2(ak[2], ak[3]);
      dq.x = pk2(aq[0], aq[1]); dq.y = pk2(aq[2], aq[3]);
      *reinterpret_cast<uint2*>(rkw + m * 16 * ST_R) = dk;
      *reinterpret_cast<uint2*>(rqw + m * 16 * ST_R) = dq;
    }
    __syncthreads();   // R visible; all sKP(K) reads complete

    // ---- scores: gather + exp + P write (into sKP alias) ----
#pragma unroll
    for (int n = 0; n < 4; ++n)
#pragma unroll
      for (int r = 0; r < 4; ++r) {
        const float relq = bf2f(gqp[(48 + r - 16 * n) * ST_R + r]);
        const float relk = bf2f(gkp[(48 + r - 16 * n) * ST_R + 16 * n]);
        const float p = __expf(fmaf(relk, 0.125f, aqk[n][r] + relq));
        lsum[r] += p;
        sKP[SWZ(16 * w + 4 * g + r, 16 * n + li)] = f2bf_hw(p);
      }
    __syncthreads();   // P visible

    // ---- O += P.V ----
    bf16x8 pA[2];
#pragma unroll
    for (int c = 0; c < 2; ++c)
      pA[c] = *reinterpret_cast<const bf16x8*>(&sKP[SWZ(16 * w + li, 32 * c + 8 * g)]);
#pragma unroll
    for (int n = 0; n < 4; ++n)
#pragma unroll
      for (int c = 0; c < 2; ++c) {
        const bf16x8 vB = *reinterpret_cast<const bf16x8*>(&sV[SWZ(16 * n + li, 32 * c + 8 * g)]);
        accO[n] = __builtin_amdgcn_mfma_f32_16x16x32_bf16(pA[c], vB, accO[n], 0, 0, 0);
      }
  }

  // ---- epilogue: single deferred l-reduction, normalize, store ----
#pragma unroll
  for (int off = 1; off < 16; off <<= 1)
#pragma unroll
    for (int r = 0; r < 4; ++r) lsum[r] += __shfl_xor(lsum[r], off, 16);
#pragma unroll
  for (int r = 0; r < 4; ++r) {
    const float inv = 1.0f / lsum[r];
    const size_t row = (size_t)(b * SEQ + q0 + 16 * w + 4 * g + r) * HID + h * HD;
#pragma unroll
    for (int n = 0; n < 4; ++n) out[row + 16 * n + li] = accO[n][r] * inv;
  }
}

extern "C" void kernel_launch(void* const* d_in, const int* in_sizes, int n_in,
                              void* d_out, int out_size, void* d_ws, size_t ws_size,
                              hipStream_t stream) {
  const float* hs = (const float*)d_in[0];
  const float* Wq = (const float*)d_in[1];
  const float* bq = (const float*)d_in[2];
  const float* Wk = (const float*)d_in[3];
  const float* bk = (const float*)d_in[4];
  const float* Wv = (const float*)d_in[5];
  const float* bv = (const float*)d_in[6];
  const float* de = (const float*)d_in[7];
  float* out = (float*)d_out;

  // Sizes: hs = 4,194,304 floats; W* = 1,048,576; de = 262,080.
  u16* Xb  = (u16*)d_ws;                 // 4,194,304 u16
  u16* Wqb = Xb + (size_t)4194304;       // 1,048,576 each
  u16* Wkb = Wqb + (size_t)1048576;
  u16* Wvb = Wkb + (size_t)1048576;
  u16* Qb  = Wvb + (size_t)1048576;      // 4,194,304 each
  u16* Kb  = Qb + (size_t)4194304;
  u16* Vb  = Kb + (size_t)4194304;
  u16* Eb  = Vb + (size_t)4194304;       // 262,080
  u16* Vtb = Xb;                         // alias: Xb dead after proj_mfma

  dim3 blk(256);
  hipLaunchKernelGGL(cvt_f32_bf16, dim3(512), blk, 0, stream, hs, Xb, 1048576);
  hipLaunchKernelGGL(cvt_f32_bf16, dim3(256), blk, 0, stream, Wq, Wqb, 262144);
  hipLaunchKernelGGL(cvt_f32_bf16, dim3(256), blk, 0, stream, Wk, Wkb, 262144);
  hipLaunchKernelGGL(cvt_f32_bf16, dim3(256), blk, 0, stream, Wv, Wvb, 262144);
  hipLaunchKernelGGL(cvt_f32_bf16, dim3(128), blk, 0, stream, de, Eb, 65520);

  hipLaunchKernelGGL(proj_mfma, dim3(24, 32), blk, 0, stream,
                     Xb, Wqb, Wkb, Wvb, bq, bk, bv, Qb, Kb, Vb);
  hipLaunchKernelGGL(transpose_v, dim3(SEQ / 64, NH, 2), blk, 0, stream, Vb, Vtb);
  hipLaunchKernelGGL(attn_mfma3, dim3(SEQ / 64, NH, 2), blk, 0, stream, Qb, Kb, Vtb, Eb, out);
}

// Round 7
// 264.108 us; speedup vs baseline: 1.4179x; 1.4179x over previous
//
#include <hip/hip_runtime.h>
#include <hip/hip_bf16.h>

#define NH 16
#define HD 64
#define SEQ 2048
#define HID 1024
#define MAXP 2048
#define ST_R 68   // u16 stride of transposed R tiles (mult of 4 for b64 writes)

typedef float f32x4 __attribute__((ext_vector_type(4)));
typedef short bf16x8 __attribute__((ext_vector_type(8)));
typedef unsigned short u16;
typedef unsigned short u16x8 __attribute__((ext_vector_type(8)));

__device__ __forceinline__ u16 f2bf_hw(float x) {
  union { __hip_bfloat16 h; u16 u; } v;
  v.h = __float2bfloat16(x);
  return v.u;
}
__device__ __forceinline__ unsigned pk2(float a, float b) {
  return (unsigned)f2bf_hw(a) | ((unsigned)f2bf_hw(b) << 16);
}
__device__ __forceinline__ float bf2f(u16 h) {
  union { unsigned u; float f; } v; v.u = ((unsigned)h) << 16;
  return v.f;
}

// XOR-swizzle for bf16 tiles with 64-elem (128B) row stride.
#define SWZ(r, c) ((r) * 64 + ((((c) >> 3) ^ ((r) & 7)) << 3) + ((c) & 7))

// async global->LDS 16B: LDS dest = wave-uniform base + lane*16; global src per-lane.
__device__ __forceinline__ void async_copy16(void* lds, const void* g) {
  __builtin_amdgcn_global_load_lds(
      (const __attribute__((address_space(1))) unsigned int*)g,
      (__attribute__((address_space(3))) unsigned int*)lds, 16, 0, 0);
}

// ---------------- fp32 -> bf16 bulk convert ----------------
__global__ __launch_bounds__(256) void cvt_f32_bf16(
    const float* __restrict__ src, u16* __restrict__ dst, int n4) {
  int i = blockIdx.x * 256 + threadIdx.x;
  const int stride = gridDim.x * 256;
  for (; i < n4; i += stride) {
    const float4 v = reinterpret_cast<const float4*>(src)[i];
    uint2 d;
    d.x = pk2(v.x, v.y);
    d.y = pk2(v.z, v.w);
    reinterpret_cast<uint2*>(dst)[i] = d;
  }
}

// ---------------- Fused Q/K/V projection: O = bf16((X @ W^T + b) * scale) ----
// Q (wsel==0) pre-scaled by 0.125 (exact in bf16) to fold 1/sqrt(64).
__global__ __launch_bounds__(256) void proj_mfma(
    const u16* __restrict__ Xb, const u16* __restrict__ W0,
    const u16* __restrict__ W1, const u16* __restrict__ W2,
    const float* __restrict__ b0, const float* __restrict__ b1,
    const float* __restrict__ b2,
    u16* __restrict__ O0, u16* __restrict__ O1, u16* __restrict__ O2) {
  __shared__ u16 sA[128 * 64];
  __shared__ u16 sB[128 * 64];
  const int t = threadIdx.x, lane = t & 63, w = t >> 6;
  const int g = lane >> 4, li = lane & 15;
  const int wsel = blockIdx.x >> 3;
  const int n0 = (blockIdx.x & 7) * 128, m0 = blockIdx.y * 128;
  const u16* Wb = wsel == 0 ? W0 : (wsel == 1 ? W1 : W2);
  const float* bias = wsel == 0 ? b0 : (wsel == 1 ? b1 : b2);
  u16* Ob = wsel == 0 ? O0 : (wsel == 1 ? O1 : O2);
  const float oscale = wsel == 0 ? 0.125f : 1.0f;
  const int wr = w >> 1, wc = w & 1;

  f32x4 acc[4][4];
#pragma unroll
  for (int i = 0; i < 4; ++i)
#pragma unroll
    for (int j = 0; j < 4; ++j) acc[i][j] = (f32x4)0.0f;

  for (int k0 = 0; k0 < HID; k0 += 64) {
    __syncthreads();
#pragma unroll
    for (int i = 0; i < 4; ++i) {
      const int idx = (w * 4 + i) * 64 + lane;
      const int row = idx >> 3, sch = (idx & 7) ^ (row & 7);
      async_copy16(&sA[(w * 4 + i) * 512], Xb + (size_t)(m0 + row) * HID + k0 + sch * 8);
      async_copy16(&sB[(w * 4 + i) * 512], Wb + (size_t)(n0 + row) * HID + k0 + sch * 8);
    }
    __syncthreads();
    bf16x8 af[4][2], bfr[4][2];
#pragma unroll
    for (int i = 0; i < 4; ++i)
#pragma unroll
      for (int c = 0; c < 2; ++c)
        af[i][c] = *reinterpret_cast<const bf16x8*>(&sA[SWZ(wr * 64 + 16 * i + li, 32 * c + 8 * g)]);
#pragma unroll
    for (int j = 0; j < 4; ++j)
#pragma unroll
      for (int c = 0; c < 2; ++c)
        bfr[j][c] = *reinterpret_cast<const bf16x8*>(&sB[SWZ(wc * 64 + 16 * j + li, 32 * c + 8 * g)]);
#pragma unroll
    for (int i = 0; i < 4; ++i)
#pragma unroll
      for (int j = 0; j < 4; ++j)
#pragma unroll
        for (int c = 0; c < 2; ++c)
          acc[i][j] = __builtin_amdgcn_mfma_f32_16x16x32_bf16(af[i][c], bfr[j][c], acc[i][j], 0, 0, 0);
  }

#pragma unroll
  for (int j = 0; j < 4; ++j) {
    const float bj = bias[n0 + wc * 64 + 16 * j + li];
#pragma unroll
    for (int i = 0; i < 4; ++i)
#pragma unroll
      for (int r = 0; r < 4; ++r)
        Ob[(size_t)(m0 + wr * 64 + 16 * i + 4 * g + r) * HID + n0 + wc * 64 + 16 * j + li] =
            f2bf_hw((acc[i][j][r] + bj) * oscale);
  }
}

// ---------------- V transpose: Vt[b][h][d][s] <- V[b][s][h*64+d] ----------------
__global__ __launch_bounds__(256) void transpose_v(
    const u16* __restrict__ Vin, u16* __restrict__ Vt) {
  __shared__ u16 tile[64 * 65];
  const int t = threadIdx.x;
  const int s0 = blockIdx.x * 64, h = blockIdx.y, b = blockIdx.z;
  const int r = t >> 2, c0 = (t & 3) * 16;
  const u16* gp = Vin + (size_t)(b * SEQ + s0 + r) * HID + h * HD + c0;
  const u16x8 a0 = *reinterpret_cast<const u16x8*>(gp);
  const u16x8 a1 = *reinterpret_cast<const u16x8*>(gp + 8);
#pragma unroll
  for (int i = 0; i < 8; ++i) { tile[r * 65 + c0 + i] = a0[i]; tile[r * 65 + c0 + 8 + i] = a1[i]; }
  __syncthreads();
  const int d = t >> 2, sc = (t & 3) * 16;
  u16x8 o0, o1;
#pragma unroll
  for (int i = 0; i < 8; ++i) {
    o0[i] = tile[(sc + i) * 65 + d];
    o1[i] = tile[(sc + 8 + i) * 65 + d];
  }
  u16* op = Vt + ((size_t)(b * NH + h) * HD + d) * SEQ + s0 + sc;
  *reinterpret_cast<u16x8*>(op) = o0;
  *reinterpret_cast<u16x8*>(op + 8) = o1;
}

// ---------------- Fused MFMA attention v4 ----------------
// R5 staging structure (E in LDS, async, full 128-row window each iter, fixed
// j = 63+qi-ki mapping -> compile-time DS gather offsets) + R6 VALU cuts
// (no-max softmax, deferred l-reduction, Q pre-scaled, P aliases dead K tile).
__global__ __launch_bounds__(256, 2) void attn_mfma4(
    const u16* __restrict__ Q, const u16* __restrict__ K,
    const u16* __restrict__ Vt, const u16* __restrict__ E,
    float* __restrict__ out) {
  __shared__ u16 sKP[64 * 64];     // K tile, then (after R-barrier) P tile
  __shared__ u16 sV[64 * 64];
  __shared__ u16 sE[128 * 64];     // E rows j = 0..127 (j=127 staged, unused)
  __shared__ u16 sRq[128 * ST_R];  // [j][qi] transposed
  __shared__ u16 sRk[128 * ST_R];  // [j][ki]

  const int t = threadIdx.x;
  const int lane = t & 63, w = t >> 6;
  const int g = lane >> 4, li = lane & 15;
  const int q0 = blockIdx.x * 64;
  const int h = blockIdx.y, b = blockIdx.z;
  const size_t qkbase = (size_t)b * SEQ * HID + (size_t)h * HD;
  const size_t vtbase = (size_t)(b * NH + h) * HD * SEQ;

  bf16x8 qA[2];
#pragma unroll
  for (int c = 0; c < 2; ++c)
    qA[c] = *reinterpret_cast<const bf16x8*>(
        Q + qkbase + (size_t)(q0 + 16 * w + li) * HID + 32 * c + 8 * g);

  f32x4 accO[4];
  float lsum[4];
#pragma unroll
  for (int n = 0; n < 4; ++n) accO[n] = (f32x4)0.0f;
#pragma unroll
  for (int r = 0; r < 4; ++r) lsum[r] = 0.0f;

  // k0-invariant gather/write bases; j = 63+qi-ki, biased so unrolled offsets
  // are non-negative compile-time constants.
  const int jb48 = 15 + 16 * w + 4 * g - li;             // in [0, 75]
  const u16* gqp = &sRq[jb48 * ST_R + 16 * w + 4 * g];   // + (48+r-16n)*ST_R + r
  const u16* gkp = &sRk[jb48 * ST_R + li];               // + (48+r-16n)*ST_R + 16n
  u16* rkw = &sRk[li * ST_R + 16 * w + 4 * g];           // + m*16*ST_R
  u16* rqw = &sRq[li * ST_R + 16 * w + 4 * g];

  for (int k0 = 0; k0 < SEQ; k0 += 64) {
    const int eb = 1984 + q0 - k0;   // global E row of j=0; in [0, 3968]
    __syncthreads();                 // prior-iter consumers of sKP/sV/sE done
    // ---- stage K, Vt (2 each) and full E window (4) per thread ----
#pragma unroll
    for (int i = 0; i < 2; ++i) {
      const int idx = (w * 2 + i) * 64 + lane;
      const int row = idx >> 3, sch = (idx & 7) ^ (row & 7);
      async_copy16(&sKP[(w * 2 + i) * 512], K + qkbase + (size_t)(k0 + row) * HID + sch * 8);
      async_copy16(&sV[(w * 2 + i) * 512], Vt + vtbase + (size_t)row * SEQ + k0 + sch * 8);
    }
#pragma unroll
    for (int i = 0; i < 4; ++i) {
      const int idx = (w * 4 + i) * 64 + lane;
      const int row = idx >> 3, sch = (idx & 7) ^ (row & 7);
      const int er = min(eb + row, 2 * MAXP - 2);  // j=127 unused; clamp in-bounds
      async_copy16(&sE[(w * 4 + i) * 512], E + (size_t)er * HD + sch * 8);
    }
    __syncthreads();

    // ---- S = Q'.K^T ----
    bf16x8 kA[2];
#pragma unroll
    for (int c = 0; c < 2; ++c)
      kA[c] = *reinterpret_cast<const bf16x8*>(&sKP[SWZ(16 * w + li, 32 * c + 8 * g)]);
    f32x4 aqk[4];
#pragma unroll
    for (int n = 0; n < 4; ++n) {
      aqk[n] = (f32x4)0.0f;
#pragma unroll
      for (int c = 0; c < 2; ++c) {
        const bf16x8 kB = *reinterpret_cast<const bf16x8*>(&sKP[SWZ(16 * n + li, 32 * c + 8 * g)]);
        aqk[n] = __builtin_amdgcn_mfma_f32_16x16x32_bf16(qA[c], kB, aqk[n], 0, 0, 0);
      }
    }
    // ---- Rq = Q'.E^T, Rk = K.E^T; packed b64 writes, transposed [j][col] ----
#pragma unroll
    for (int m = 0; m < 8; ++m) {
      bf16x8 eB[2];
#pragma unroll
      for (int c = 0; c < 2; ++c)
        eB[c] = *reinterpret_cast<const bf16x8*>(&sE[SWZ(16 * m + li, 32 * c + 8 * g)]);
      f32x4 ak = (f32x4)0.0f, aq = (f32x4)0.0f;
#pragma unroll
      for (int c = 0; c < 2; ++c) {
        ak = __builtin_amdgcn_mfma_f32_16x16x32_bf16(kA[c], eB[c], ak, 0, 0, 0);
        aq = __builtin_amdgcn_mfma_f32_16x16x32_bf16(qA[c], eB[c], aq, 0, 0, 0);
      }
      uint2 dk, dq;
      dk.x = pk2(ak[0], ak[1]); dk.y = pk2(ak[2], ak[3]);
      dq.x = pk2(aq[0], aq[1]); dq.y = pk2(aq[2], aq[3]);
      *reinterpret_cast<uint2*>(rkw + m * 16 * ST_R) = dk;
      *reinterpret_cast<uint2*>(rqw + m * 16 * ST_R) = dq;
    }
    __syncthreads();   // R visible; all sKP(K) reads complete

    // ---- scores: gather + exp + P write (into sKP alias) ----
#pragma unroll
    for (int n = 0; n < 4; ++n)
#pragma unroll
      for (int r = 0; r < 4; ++r) {
        const float relq = bf2f(gqp[(48 + r - 16 * n) * ST_R + r]);
        const float relk = bf2f(gkp[(48 + r - 16 * n) * ST_R + 16 * n]);
        const float p = __expf(fmaf(relk, 0.125f, aqk[n][r] + relq));
        lsum[r] += p;
        sKP[SWZ(16 * w + 4 * g + r, 16 * n + li)] = f2bf_hw(p);
      }
    __syncthreads();   // P visible

    // ---- O += P.V ----
    bf16x8 pA[2];
#pragma unroll
    for (int c = 0; c < 2; ++c)
      pA[c] = *reinterpret_cast<const bf16x8*>(&sKP[SWZ(16 * w + li, 32 * c + 8 * g)]);
#pragma unroll
    for (int n = 0; n < 4; ++n)
#pragma unroll
      for (int c = 0; c < 2; ++c) {
        const bf16x8 vB = *reinterpret_cast<const bf16x8*>(&sV[SWZ(16 * n + li, 32 * c + 8 * g)]);
        accO[n] = __builtin_amdgcn_mfma_f32_16x16x32_bf16(pA[c], vB, accO[n], 0, 0, 0);
      }
  }

  // ---- epilogue: single deferred l-reduction, normalize, store ----
#pragma unroll
  for (int off = 1; off < 16; off <<= 1)
#pragma unroll
    for (int r = 0; r < 4; ++r) lsum[r] += __shfl_xor(lsum[r], off, 16);
#pragma unroll
  for (int r = 0; r < 4; ++r) {
    const float inv = 1.0f / lsum[r];
    const size_t row = (size_t)(b * SEQ + q0 + 16 * w + 4 * g + r) * HID + h * HD;
#pragma unroll
    for (int n = 0; n < 4; ++n) out[row + 16 * n + li] = accO[n][r] * inv;
  }
}

extern "C" void kernel_launch(void* const* d_in, const int* in_sizes, int n_in,
                              void* d_out, int out_size, void* d_ws, size_t ws_size,
                              hipStream_t stream) {
  const float* hs = (const float*)d_in[0];
  const float* Wq = (const float*)d_in[1];
  const float* bq = (const float*)d_in[2];
  const float* Wk = (const float*)d_in[3];
  const float* bk = (const float*)d_in[4];
  const float* Wv = (const float*)d_in[5];
  const float* bv = (const float*)d_in[6];
  const float* de = (const float*)d_in[7];
  float* out = (float*)d_out;

  // Sizes: hs = 4,194,304 floats; W* = 1,048,576; de = 262,080.
  u16* Xb  = (u16*)d_ws;                 // 4,194,304 u16
  u16* Wqb = Xb + (size_t)4194304;       // 1,048,576 each
  u16* Wkb = Wqb + (size_t)1048576;
  u16* Wvb = Wkb + (size_t)1048576;
  u16* Qb  = Wvb + (size_t)1048576;      // 4,194,304 each
  u16* Kb  = Qb + (size_t)4194304;
  u16* Vb  = Kb + (size_t)4194304;
  u16* Eb  = Vb + (size_t)4194304;       // 262,080
  u16* Vtb = Xb;                         // alias: Xb dead after proj_mfma

  dim3 blk(256);
  hipLaunchKernelGGL(cvt_f32_bf16, dim3(512), blk, 0, stream, hs, Xb, 1048576);
  hipLaunchKernelGGL(cvt_f32_bf16, dim3(256), blk, 0, stream, Wq, Wqb, 262144);
  hipLaunchKernelGGL(cvt_f32_bf16, dim3(256), blk, 0, stream, Wk, Wkb, 262144);
  hipLaunchKernelGGL(cvt_f32_bf16, dim3(256), blk, 0, stream, Wv, Wvb, 262144);
  hipLaunchKernelGGL(cvt_f32_bf16, dim3(128), blk, 0, stream, de, Eb, 65520);

  hipLaunchKernelGGL(proj_mfma, dim3(24, 32), blk, 0, stream,
                     Xb, Wqb, Wkb, Wvb, bq, bk, bv, Qb, Kb, Vb);
  hipLaunchKernelGGL(transpose_v, dim3(SEQ / 64, NH, 2), blk, 0, stream, Vb, Vtb);
  hipLaunchKernelGGL(attn_mfma4, dim3(SEQ / 64, NH, 2), blk, 0, stream, Qb, Kb, Vtb, Eb, out);
}

// Round 8
// 248.208 us; speedup vs baseline: 1.5088x; 1.0641x over previous
//
#include <hip/hip_runtime.h>
#include <hip/hip_bf16.h>

#define NH 16
#define HD 64
#define SEQ 2048
#define HID 1024
#define MAXP 2048
#define ST_R 68   // u16 stride of transposed R tiles (mult of 4 for b64 writes)

typedef float f32x4 __attribute__((ext_vector_type(4)));
typedef short bf16x8 __attribute__((ext_vector_type(8)));
typedef unsigned short u16;
typedef unsigned short u16x8 __attribute__((ext_vector_type(8)));

__device__ __forceinline__ u16 f2bf_hw(float x) {
  union { __hip_bfloat16 h; u16 u; } v;
  v.h = __float2bfloat16(x);
  return v.u;
}
__device__ __forceinline__ unsigned pk2(float a, float b) {
  return (unsigned)f2bf_hw(a) | ((unsigned)f2bf_hw(b) << 16);
}
__device__ __forceinline__ float bf2f(u16 h) {
  union { unsigned u; float f; } v; v.u = ((unsigned)h) << 16;
  return v.f;
}

// XOR-swizzle for bf16 tiles with 64-elem (128B) row stride.
#define SWZ(r, c) ((r) * 64 + ((((c) >> 3) ^ ((r) & 7)) << 3) + ((c) & 7))

// async global->LDS 16B: LDS dest = wave-uniform base + lane*16; global src per-lane.
__device__ __forceinline__ void async_copy16(void* lds, const void* g) {
  __builtin_amdgcn_global_load_lds(
      (const __attribute__((address_space(1))) unsigned int*)g,
      (__attribute__((address_space(3))) unsigned int*)lds, 16, 0, 0);
}
__device__ __forceinline__ void vwait0() { asm volatile("s_waitcnt vmcnt(0)" ::: "memory"); }
__device__ __forceinline__ void lwait0() { asm volatile("s_waitcnt lgkmcnt(0)" ::: "memory"); }

// ---------------- fp32 -> bf16 bulk convert ----------------
__global__ __launch_bounds__(256) void cvt_f32_bf16(
    const float* __restrict__ src, u16* __restrict__ dst, int n4) {
  int i = blockIdx.x * 256 + threadIdx.x;
  const int stride = gridDim.x * 256;
  for (; i < n4; i += stride) {
    const float4 v = reinterpret_cast<const float4*>(src)[i];
    uint2 d;
    d.x = pk2(v.x, v.y);
    d.y = pk2(v.z, v.w);
    reinterpret_cast<uint2*>(dst)[i] = d;
  }
}

// ---------------- Fused Q/K/V projection: O = bf16((X @ W^T + b) * scale) ----
// Q (wsel==0) pre-scaled by 0.125 (exact in bf16) to fold 1/sqrt(64).
__global__ __launch_bounds__(256) void proj_mfma(
    const u16* __restrict__ Xb, const u16* __restrict__ W0,
    const u16* __restrict__ W1, const u16* __restrict__ W2,
    const float* __restrict__ b0, const float* __restrict__ b1,
    const float* __restrict__ b2,
    u16* __restrict__ O0, u16* __restrict__ O1, u16* __restrict__ O2) {
  __shared__ u16 sA[128 * 64];
  __shared__ u16 sB[128 * 64];
  const int t = threadIdx.x, lane = t & 63, w = t >> 6;
  const int g = lane >> 4, li = lane & 15;
  const int wsel = blockIdx.x >> 3;
  const int n0 = (blockIdx.x & 7) * 128, m0 = blockIdx.y * 128;
  const u16* Wb = wsel == 0 ? W0 : (wsel == 1 ? W1 : W2);
  const float* bias = wsel == 0 ? b0 : (wsel == 1 ? b1 : b2);
  u16* Ob = wsel == 0 ? O0 : (wsel == 1 ? O1 : O2);
  const float oscale = wsel == 0 ? 0.125f : 1.0f;
  const int wr = w >> 1, wc = w & 1;

  f32x4 acc[4][4];
#pragma unroll
  for (int i = 0; i < 4; ++i)
#pragma unroll
    for (int j = 0; j < 4; ++j) acc[i][j] = (f32x4)0.0f;

  for (int k0 = 0; k0 < HID; k0 += 64) {
    __syncthreads();
#pragma unroll
    for (int i = 0; i < 4; ++i) {
      const int idx = (w * 4 + i) * 64 + lane;
      const int row = idx >> 3, sch = (idx & 7) ^ (row & 7);
      async_copy16(&sA[(w * 4 + i) * 512], Xb + (size_t)(m0 + row) * HID + k0 + sch * 8);
      async_copy16(&sB[(w * 4 + i) * 512], Wb + (size_t)(n0 + row) * HID + k0 + sch * 8);
    }
    __syncthreads();
    bf16x8 af[4][2], bfr[4][2];
#pragma unroll
    for (int i = 0; i < 4; ++i)
#pragma unroll
      for (int c = 0; c < 2; ++c)
        af[i][c] = *reinterpret_cast<const bf16x8*>(&sA[SWZ(wr * 64 + 16 * i + li, 32 * c + 8 * g)]);
#pragma unroll
    for (int j = 0; j < 4; ++j)
#pragma unroll
      for (int c = 0; c < 2; ++c)
        bfr[j][c] = *reinterpret_cast<const bf16x8*>(&sB[SWZ(wc * 64 + 16 * j + li, 32 * c + 8 * g)]);
#pragma unroll
    for (int i = 0; i < 4; ++i)
#pragma unroll
      for (int j = 0; j < 4; ++j)
#pragma unroll
        for (int c = 0; c < 2; ++c)
          acc[i][j] = __builtin_amdgcn_mfma_f32_16x16x32_bf16(af[i][c], bfr[j][c], acc[i][j], 0, 0, 0);
  }

#pragma unroll
  for (int j = 0; j < 4; ++j) {
    const float bj = bias[n0 + wc * 64 + 16 * j + li];
#pragma unroll
    for (int i = 0; i < 4; ++i)
#pragma unroll
      for (int r = 0; r < 4; ++r)
        Ob[(size_t)(m0 + wr * 64 + 16 * i + 4 * g + r) * HID + n0 + wc * 64 + 16 * j + li] =
            f2bf_hw((acc[i][j][r] + bj) * oscale);
  }
}

// ---------------- V transpose: Vt[b][h][d][s] <- V[b][s][h*64+d] ----------------
__global__ __launch_bounds__(256) void transpose_v(
    const u16* __restrict__ Vin, u16* __restrict__ Vt) {
  __shared__ u16 tile[64 * 65];
  const int t = threadIdx.x;
  const int s0 = blockIdx.x * 64, h = blockIdx.y, b = blockIdx.z;
  const int r = t >> 2, c0 = (t & 3) * 16;
  const u16* gp = Vin + (size_t)(b * SEQ + s0 + r) * HID + h * HD + c0;
  const u16x8 a0 = *reinterpret_cast<const u16x8*>(gp);
  const u16x8 a1 = *reinterpret_cast<const u16x8*>(gp + 8);
#pragma unroll
  for (int i = 0; i < 8; ++i) { tile[r * 65 + c0 + i] = a0[i]; tile[r * 65 + c0 + 8 + i] = a1[i]; }
  __syncthreads();
  const int d = t >> 2, sc = (t & 3) * 16;
  u16x8 o0, o1;
#pragma unroll
  for (int i = 0; i < 8; ++i) {
    o0[i] = tile[(sc + i) * 65 + d];
    o1[i] = tile[(sc + 8 + i) * 65 + d];
  }
  u16* op = Vt + ((size_t)(b * NH + h) * HD + d) * SEQ + s0 + sc;
  *reinterpret_cast<u16x8*>(op) = o0;
  *reinterpret_cast<u16x8*>(op + 8) = o1;
}

// ---------------- Fused MFMA attention v5: 2-barrier pipeline ----------------
// Per iter: [#1 bar] issue V(t),K(t+1) -> QK -> R-GEMM+writes -> vm0+lgkm0 ->
// [#2 bar] issue E(t+1) -> scores (P into dead K buf) -> PV -> vm0 -> loop.
// Every staged tile is in flight >=1 full phase before its wait; all
// cross-wave reads are protected by (own-drain before barrier) -> barrier.
__global__ __launch_bounds__(256, 2) void attn_mfma5(
    const u16* __restrict__ Q, const u16* __restrict__ K,
    const u16* __restrict__ Vt, const u16* __restrict__ E,
    float* __restrict__ out) {
  __shared__ u16 sK0[64 * 64];     // K buffers; current one becomes P after #2
  __shared__ u16 sK1[64 * 64];
  __shared__ u16 sV[64 * 64];
  __shared__ u16 sE[128 * 64];
  __shared__ u16 sRq[128 * ST_R];  // [j][qi] transposed
  __shared__ u16 sRk[128 * ST_R];  // [j][ki]

  const int t = threadIdx.x;
  const int lane = t & 63, w = t >> 6;
  const int g = lane >> 4, li = lane & 15;
  const int q0 = blockIdx.x * 64;
  const int h = blockIdx.y, b = blockIdx.z;
  const size_t qkbase = (size_t)b * SEQ * HID + (size_t)h * HD;
  const size_t vtbase = (size_t)(b * NH + h) * HD * SEQ;

  bf16x8 qA[2];
#pragma unroll
  for (int c = 0; c < 2; ++c)
    qA[c] = *reinterpret_cast<const bf16x8*>(
        Q + qkbase + (size_t)(q0 + 16 * w + li) * HID + 32 * c + 8 * g);

  f32x4 accO[4];
  float lsum[4];
#pragma unroll
  for (int n = 0; n < 4; ++n) accO[n] = (f32x4)0.0f;
#pragma unroll
  for (int r = 0; r < 4; ++r) lsum[r] = 0.0f;

  // k0-invariant gather/write bases; j = 63+qi-ki, biased so unrolled offsets
  // are non-negative compile-time constants.
  const int jb48 = 15 + 16 * w + 4 * g - li;             // in [0, 75]
  const u16* gqp = &sRq[jb48 * ST_R + 16 * w + 4 * g];   // + (48+r-16n)*ST_R + r
  const u16* gkp = &sRk[jb48 * ST_R + li];               // + (48+r-16n)*ST_R + 16n
  u16* rkw = &sRk[li * ST_R + 16 * w + 4 * g];           // + m*16*ST_R
  u16* rqw = &sRq[li * ST_R + 16 * w + 4 * g];

  // staging geometry (per wave: 2 K instr, 2 V instr, 4 E instr)
  const int sidx2 = w * 2 * 64 + lane;                 // base idx for 2-instr stages
  const int sidx4 = w * 4 * 64 + lane;                 // base idx for 4-instr stages

  // ---- prologue: stage K(0), E(0); drain ----
  {
    const int eb0 = 1984 + q0;
#pragma unroll
    for (int i = 0; i < 2; ++i) {
      const int idx = sidx2 + i * 64;
      const int row = idx >> 3, sch = (idx & 7) ^ (row & 7);
      async_copy16(&sK0[(w * 2 + i) * 512], K + qkbase + (size_t)row * HID + sch * 8);
    }
#pragma unroll
    for (int i = 0; i < 4; ++i) {
      const int idx = sidx4 + i * 64;
      const int row = idx >> 3, sch = (idx & 7) ^ (row & 7);
      const int er = min(max(eb0 + row, 0), 2 * MAXP - 2);
      async_copy16(&sE[(w * 4 + i) * 512], E + (size_t)er * HD + sch * 8);
    }
    vwait0();
  }

  for (int k0 = 0; k0 < SEQ; k0 += 64) {
    const int p = (k0 >> 6) & 1;
    u16* kcur = p ? sK1 : sK0;
    u16* knxt = p ? sK0 : sK1;

    __builtin_amdgcn_s_barrier();   // #1: K(t),E(t) visible; sV/knxt reusable
    // ---- issue V(t) and K(t+1) ----
#pragma unroll
    for (int i = 0; i < 2; ++i) {
      const int idx = sidx2 + i * 64;
      const int row = idx >> 3, sch = (idx & 7) ^ (row & 7);
      async_copy16(&sV[(w * 2 + i) * 512], Vt + vtbase + (size_t)row * SEQ + k0 + sch * 8);
      async_copy16(&knxt[(w * 2 + i) * 512], K + qkbase + (size_t)(k0 + 64 + row) * HID + sch * 8);
    }

    // ---- S = Q'.K^T ----
    bf16x8 kA[2];
#pragma unroll
    for (int c = 0; c < 2; ++c)
      kA[c] = *reinterpret_cast<const bf16x8*>(&kcur[SWZ(16 * w + li, 32 * c + 8 * g)]);
    f32x4 aqk[4];
#pragma unroll
    for (int n = 0; n < 4; ++n) {
      aqk[n] = (f32x4)0.0f;
#pragma unroll
      for (int c = 0; c < 2; ++c) {
        const bf16x8 kB = *reinterpret_cast<const bf16x8*>(&kcur[SWZ(16 * n + li, 32 * c + 8 * g)]);
        aqk[n] = __builtin_amdgcn_mfma_f32_16x16x32_bf16(qA[c], kB, aqk[n], 0, 0, 0);
      }
    }
    // ---- Rq = Q'.E^T, Rk = K.E^T; packed b64 writes, transposed [j][col] ----
    __builtin_amdgcn_s_setprio(1);
#pragma unroll
    for (int m = 0; m < 8; ++m) {
      bf16x8 eB[2];
#pragma unroll
      for (int c = 0; c < 2; ++c)
        eB[c] = *reinterpret_cast<const bf16x8*>(&sE[SWZ(16 * m + li, 32 * c + 8 * g)]);
      f32x4 ak = (f32x4)0.0f, aq = (f32x4)0.0f;
#pragma unroll
      for (int c = 0; c < 2; ++c) {
        ak = __builtin_amdgcn_mfma_f32_16x16x32_bf16(kA[c], eB[c], ak, 0, 0, 0);
        aq = __builtin_amdgcn_mfma_f32_16x16x32_bf16(qA[c], eB[c], aq, 0, 0, 0);
      }
      uint2 dk, dq;
      dk.x = pk2(ak[0], ak[1]); dk.y = pk2(ak[2], ak[3]);
      dq.x = pk2(aq[0], aq[1]); dq.y = pk2(aq[2], aq[3]);
      *reinterpret_cast<uint2*>(rkw + m * 16 * ST_R) = dk;
      *reinterpret_cast<uint2*>(rqw + m * 16 * ST_R) = dq;
    }
    __builtin_amdgcn_s_setprio(0);

    vwait0();                       // V(t), K(t+1) landed (in flight since top)
    lwait0();                       // R-writes retired
    __builtin_amdgcn_s_barrier();   // #2: sRk/sRq + sV + K(t+1) visible to all

    // ---- issue E(t+1) (all sE reads happened before #2) ----
    {
      const int ebn = 1920 + q0 - k0;  // eb(t+1) = 1984 + q0 - (k0+64)
#pragma unroll
      for (int i = 0; i < 4; ++i) {
        const int idx = sidx4 + i * 64;
        const int row = idx >> 3, sch = (idx & 7) ^ (row & 7);
        const int er = min(max(ebn + row, 0), 2 * MAXP - 2);
        async_copy16(&sE[(w * 4 + i) * 512], E + (size_t)er * HD + sch * 8);
      }
    }

    // ---- scores: gather + exp + P write (into kcur, dead K tile) ----
#pragma unroll
    for (int n = 0; n < 4; ++n)
#pragma unroll
      for (int r = 0; r < 4; ++r) {
        const float relq = bf2f(gqp[(48 + r - 16 * n) * ST_R + r]);
        const float relk = bf2f(gkp[(48 + r - 16 * n) * ST_R + 16 * n]);
        const float pr = __expf(fmaf(relk, 0.125f, aqk[n][r] + relq));
        lsum[r] += pr;
        kcur[SWZ(16 * w + 4 * g + r, 16 * n + li)] = f2bf_hw(pr);
      }

    // ---- O += P.V (P rows are wave-local; compiler orders via lgkmcnt) ----
    bf16x8 pA[2];
#pragma unroll
    for (int c = 0; c < 2; ++c)
      pA[c] = *reinterpret_cast<const bf16x8*>(&kcur[SWZ(16 * w + li, 32 * c + 8 * g)]);
#pragma unroll
    for (int n = 0; n < 4; ++n)
#pragma unroll
      for (int c = 0; c < 2; ++c) {
        const bf16x8 vB = *reinterpret_cast<const bf16x8*>(&sV[SWZ(16 * n + li, 32 * c + 8 * g)]);
        accO[n] = __builtin_amdgcn_mfma_f32_16x16x32_bf16(pA[c], vB, accO[n], 0, 0, 0);
      }

    vwait0();                       // E(t+1) landed (in flight since #2)
  }

  // ---- epilogue: single deferred l-reduction, normalize, store ----
#pragma unroll
  for (int off = 1; off < 16; off <<= 1)
#pragma unroll
    for (int r = 0; r < 4; ++r) lsum[r] += __shfl_xor(lsum[r], off, 16);
#pragma unroll
  for (int r = 0; r < 4; ++r) {
    const float inv = 1.0f / lsum[r];
    const size_t row = (size_t)(b * SEQ + q0 + 16 * w + 4 * g + r) * HID + h * HD;
#pragma unroll
    for (int n = 0; n < 4; ++n) out[row + 16 * n + li] = accO[n][r] * inv;
  }
}

extern "C" void kernel_launch(void* const* d_in, const int* in_sizes, int n_in,
                              void* d_out, int out_size, void* d_ws, size_t ws_size,
                              hipStream_t stream) {
  const float* hs = (const float*)d_in[0];
  const float* Wq = (const float*)d_in[1];
  const float* bq = (const float*)d_in[2];
  const float* Wk = (const float*)d_in[3];
  const float* bk = (const float*)d_in[4];
  const float* Wv = (const float*)d_in[5];
  const float* bv = (const float*)d_in[6];
  const float* de = (const float*)d_in[7];
  float* out = (float*)d_out;

  // Sizes: hs = 4,194,304 floats; W* = 1,048,576; de = 262,080.
  u16* Xb  = (u16*)d_ws;                 // 4,194,304 u16
  u16* Wqb = Xb + (size_t)4194304;       // 1,048,576 each
  u16* Wkb = Wqb + (size_t)1048576;
  u16* Wvb = Wkb + (size_t)1048576;
  u16* Qb  = Wvb + (size_t)1048576;      // 4,194,304 each
  u16* Kb  = Qb + (size_t)4194304;
  u16* Vb  = Kb + (size_t)4194304;
  u16* Eb  = Vb + (size_t)4194304;       // 262,080
  u16* Vtb = Xb;                         // alias: Xb dead after proj_mfma

  dim3 blk(256);
  hipLaunchKernelGGL(cvt_f32_bf16, dim3(512), blk, 0, stream, hs, Xb, 1048576);
  hipLaunchKernelGGL(cvt_f32_bf16, dim3(256), blk, 0, stream, Wq, Wqb, 262144);
  hipLaunchKernelGGL(cvt_f32_bf16, dim3(256), blk, 0, stream, Wk, Wkb, 262144);
  hipLaunchKernelGGL(cvt_f32_bf16, dim3(256), blk, 0, stream, Wv, Wvb, 262144);
  hipLaunchKernelGGL(cvt_f32_bf16, dim3(128), blk, 0, stream, de, Eb, 65520);

  hipLaunchKernelGGL(proj_mfma, dim3(24, 32), blk, 0, stream,
                     Xb, Wqb, Wkb, Wvb, bq, bk, bv, Qb, Kb, Vb);
  hipLaunchKernelGGL(transpose_v, dim3(SEQ / 64, NH, 2), blk, 0, stream, Vb, Vtb);
  hipLaunchKernelGGL(attn_mfma5, dim3(SEQ / 64, NH, 2), blk, 0, stream, Qb, Kb, Vtb, Eb, out);
}